// Round 1
// baseline (2802.058 us; speedup 1.0000x reference)
//
#include <hip/hip_runtime.h>
#include <math.h>

#define BN_EPS 1e-5f

constexpr int BB   = 8;
constexpr int CC   = 256;
constexpr int NN   = 2304;          // 48*48
constexpr int MTOT = BB * NN;       // 18432
constexpr int NSPLIT = 3;           // m-splits for attention balance (18 tiles / 3)
constexpr int MT   = 128;           // m-tile
constexpr int TPS  = 6;             // m-tiles per split

union F4 { float4 v; float f[4]; };

// ---------------- kernel 1: QKV (kT/qT/vT[b][n][c] = sum_c' W[c][c'] x[b][c'][n]) ----
__global__ __launch_bounds__(256) void qkv_gemm(
    const float* __restrict__ x, const float* __restrict__ Wk,
    const float* __restrict__ Wq, const float* __restrict__ Wv,
    float* __restrict__ kT, float* __restrict__ qT, float* __restrict__ vT)
{
  const int mat = blockIdx.z >> 3;
  const int b   = blockIdx.z & 7;
  const int n0  = blockIdx.y * 64;
  const int c0  = blockIdx.x * 64;
  const float* Wm = (mat == 0) ? Wk : (mat == 1) ? Wq : Wv;
  float* outp     = (mat == 0) ? kT : (mat == 1) ? qT : vT;

  __shared__ alignas(16) float a_s[16][64];   // [kk][n]
  __shared__ alignas(16) float w_s[16][68];   // [kk][c]
  const int tid = threadIdx.x;
  const int tx = tid & 15, ty = tid >> 4;
  float acc[4][4] = {};
  const float* xb = x + (size_t)b * CC * NN;
  for (int ck = 0; ck < CC; ck += 16) {
#pragma unroll
    for (int t = 0; t < 4; ++t) {
      int e = tid + t * 256;  // 1024
      a_s[e >> 6][e & 63] = xb[(size_t)(ck + (e >> 6)) * NN + n0 + (e & 63)];
      w_s[e & 15][e >> 4] = Wm[(c0 + (e >> 4)) * CC + ck + (e & 15)];
    }
    __syncthreads();
#pragma unroll
    for (int kk = 0; kk < 16; ++kk) {
      F4 a4, w4;
      a4.v = *(const float4*)&a_s[kk][ty * 4];
      w4.v = *(const float4*)&w_s[kk][tx * 4];
#pragma unroll
      for (int i = 0; i < 4; ++i)
#pragma unroll
        for (int j = 0; j < 4; ++j) acc[i][j] += a4.f[i] * w4.f[j];
    }
    __syncthreads();
  }
  float* ob = outp + (size_t)b * NN * CC;
#pragma unroll
  for (int i = 0; i < 4; ++i) {
    F4 v4;
#pragma unroll
    for (int j = 0; j < 4; ++j) v4.f[j] = acc[i][j];
    *(float4*)&ob[(size_t)(n0 + ty * 4 + i) * CC + c0 + tx * 4] = v4.v;
  }
}

// ---------------- shared S-tile compute: acc[i][j] = S[n0+4ty+i][m0+8tx+j] --------
__device__ __forceinline__ void compute_S(
    const float* __restrict__ kb, const float* __restrict__ qb,
    int n0, int m0, int tid, int tx, int ty,
    float K_sT[16][68], float Q_sT[16][132], float acc[4][8])
{
#pragma unroll
  for (int i = 0; i < 4; ++i)
#pragma unroll
    for (int j = 0; j < 8; ++j) acc[i][j] = 0.f;
  for (int ck = 0; ck < CC; ck += 16) {
#pragma unroll
    for (int t = 0; t < 4; ++t) {
      int e = tid + t * 256;  // 1024 = 64n x 16c
      K_sT[e & 15][e >> 4] = kb[(size_t)(n0 + (e >> 4)) * CC + ck + (e & 15)];
    }
#pragma unroll
    for (int t = 0; t < 8; ++t) {
      int e = tid + t * 256;  // 2048 = 128m x 16c
      Q_sT[e & 15][e >> 4] = qb[(size_t)(m0 + (e >> 4)) * CC + ck + (e & 15)];
    }
    __syncthreads();
#pragma unroll
    for (int kk = 0; kk < 16; ++kk) {
      F4 a4, b4a, b4b;
      a4.v  = *(const float4*)&K_sT[kk][ty * 4];
      b4a.v = *(const float4*)&Q_sT[kk][tx * 8];
      b4b.v = *(const float4*)&Q_sT[kk][tx * 8 + 4];
#pragma unroll
      for (int i = 0; i < 4; ++i) {
#pragma unroll
        for (int j = 0; j < 4; ++j) acc[i][j]     += a4.f[i] * b4a.f[j];
#pragma unroll
        for (int j = 0; j < 4; ++j) acc[i][j + 4] += a4.f[i] * b4b.f[j];
      }
    }
    __syncthreads();
  }
}

// ---------------- kernel 2A: row stats (partial per m-split) ----------------------
__global__ __launch_bounds__(256) void attn_stats(
    const float* __restrict__ kT, const float* __restrict__ qT,
    float* __restrict__ pmax, float* __restrict__ psum)
{
  const int b = blockIdx.z, split = blockIdx.y;
  const int n0 = blockIdx.x * 64;
  __shared__ alignas(16) float K_sT[16][68];
  __shared__ alignas(16) float Q_sT[16][132];
  const int tid = threadIdx.x, tx = tid & 15, ty = tid >> 4;
  const float* kb = kT + (size_t)b * NN * CC;
  const float* qb = qT + (size_t)b * NN * CC;
  float rmax[4], rsum[4];
#pragma unroll
  for (int i = 0; i < 4; ++i) { rmax[i] = -INFINITY; rsum[i] = 0.f; }
  for (int t = 0; t < TPS; ++t) {
    const int m0 = (split * TPS + t) * MT;
    float acc[4][8];
    compute_S(kb, qb, n0, m0, tid, tx, ty, K_sT, Q_sT, acc);
#pragma unroll
    for (int i = 0; i < 4; ++i) {
      float tm = acc[i][0];
#pragma unroll
      for (int j = 1; j < 8; ++j) tm = fmaxf(tm, acc[i][j]);
      const float mn = fmaxf(rmax[i], tm);
      float s = 0.f;
#pragma unroll
      for (int j = 0; j < 8; ++j) s += __expf(acc[i][j] - mn);
      rsum[i] = rsum[i] * __expf(rmax[i] - mn) + s;
      rmax[i] = mn;
    }
  }
#pragma unroll
  for (int i = 0; i < 4; ++i) {
    for (int off = 1; off < 16; off <<= 1) {   // reduce across the 16 tx lanes
      const float om = __shfl_xor(rmax[i], off);
      const float os = __shfl_xor(rsum[i], off);
      const float mn = fmaxf(rmax[i], om);
      rsum[i] = rsum[i] * __expf(rmax[i] - mn) + os * __expf(om - mn);
      rmax[i] = mn;
    }
    if (tx == 0) {
      const size_t idx = (size_t)(split * BB + b) * NN + n0 + ty * 4 + i;
      pmax[idx] = rmax[i];
      psum[idx] = rsum[i];
    }
  }
}

// ---------------- merge split stats -> final rowmax, 1/rowsum ---------------------
__global__ void merge_stats(const float* __restrict__ pmax, const float* __restrict__ psum,
                            float* __restrict__ rowmax, float* __restrict__ rowinv)
{
  const int r = blockIdx.x * 256 + threadIdx.x;
  const float m0 = pmax[r], m1 = pmax[MTOT + r], m2 = pmax[2 * MTOT + r];
  const float M = fmaxf(m0, fmaxf(m1, m2));
  const float L = psum[r] * __expf(m0 - M) + psum[MTOT + r] * __expf(m1 - M)
                + psum[2 * MTOT + r] * __expf(m2 - M);
  rowmax[r] = M;
  rowinv[r] = 1.0f / L;
}

// ---------------- kernel 2B: PV with final stats (partial O per m-split) ----------
__global__ __launch_bounds__(256) void attn_pv(
    const float* __restrict__ kT, const float* __restrict__ qT,
    const float* __restrict__ vT,
    const float* __restrict__ rowmax, const float* __restrict__ rowinv,
    float* __restrict__ Opart)
{
  const int b = blockIdx.z, split = blockIdx.y;
  const int n0 = blockIdx.x * 64;
  __shared__ alignas(16) float K_sT[16][68];
  __shared__ alignas(16) float Q_sT[16][132];
  __shared__ alignas(16) float P_s[64][132];
  __shared__ alignas(16) float V_s[32][132];
  const int tid = threadIdx.x, tx = tid & 15, ty = tid >> 4;
  const float* kb = kT + (size_t)b * NN * CC;
  const float* qb = qT + (size_t)b * NN * CC;
  const float* vb = vT + (size_t)b * NN * CC;
  float rmx[4], rin[4];
#pragma unroll
  for (int i = 0; i < 4; ++i) {
    const int n = b * NN + n0 + ty * 4 + i;
    rmx[i] = rowmax[n];
    rin[i] = rowinv[n];
  }
  float o[2][4][8] = {};
  for (int t = 0; t < TPS; ++t) {
    const int m0 = (split * TPS + t) * MT;
    float acc[4][8];
    compute_S(kb, qb, n0, m0, tid, tx, ty, K_sT, Q_sT, acc);
#pragma unroll
    for (int i = 0; i < 4; ++i) {
      F4 pa, pb;
#pragma unroll
      for (int j = 0; j < 4; ++j) {
        pa.f[j] = __expf(acc[i][j]     - rmx[i]) * rin[i];
        pb.f[j] = __expf(acc[i][j + 4] - rmx[i]) * rin[i];
      }
      *(float4*)&P_s[ty * 4 + i][tx * 8]     = pa.v;
      *(float4*)&P_s[ty * 4 + i][tx * 8 + 4] = pb.v;
    }
#pragma unroll
    for (int ch = 0; ch < 2; ++ch) {
      for (int mi = 0; mi < 4; ++mi) {
        __syncthreads();   // P_s ready / previous V_s consumers done
#pragma unroll
        for (int tt = 0; tt < 16; ++tt) {
          int e = tid + tt * 256;   // 4096 = 32m x 128c
          V_s[e >> 7][e & 127] =
              vb[(size_t)(m0 + mi * 32 + (e >> 7)) * CC + ch * 128 + (e & 127)];
        }
        __syncthreads();
#pragma unroll
        for (int mm = 0; mm < 32; mm += 4) {
          F4 p4[4];
#pragma unroll
          for (int i = 0; i < 4; ++i)
            p4[i].v = *(const float4*)&P_s[ty * 4 + i][mi * 32 + mm];
#pragma unroll
          for (int m2 = 0; m2 < 4; ++m2) {
            F4 va, vbb;
            va.v  = *(const float4*)&V_s[mm + m2][tx * 8];
            vbb.v = *(const float4*)&V_s[mm + m2][tx * 8 + 4];
#pragma unroll
            for (int i = 0; i < 4; ++i) {
#pragma unroll
              for (int j = 0; j < 4; ++j) o[ch][i][j]     += p4[i].f[m2] * va.f[j];
#pragma unroll
              for (int j = 0; j < 4; ++j) o[ch][i][j + 4] += p4[i].f[m2] * vbb.f[j];
            }
          }
        }
      }
    }
  }
  float* op = Opart + (size_t)split * MTOT * CC;
#pragma unroll
  for (int ch = 0; ch < 2; ++ch)
#pragma unroll
    for (int i = 0; i < 4; ++i) {
      const size_t base = ((size_t)b * NN + n0 + ty * 4 + i) * CC + ch * 128 + tx * 8;
      F4 v4a, v4b;
#pragma unroll
      for (int j = 0; j < 4; ++j) { v4a.f[j] = o[ch][i][j]; v4b.f[j] = o[ch][i][j + 4]; }
      *(float4*)&op[base]     = v4a.v;
      *(float4*)&op[base + 4] = v4b.v;
    }
}

// ---------------- zero BN stats (ws is poisoned each launch) ----------------------
__global__ void zero_stats(float* __restrict__ s)
{
  s[blockIdx.x * 256 + threadIdx.x] = 0.f;
}

// ---------------- kernel 3a: output projection + bias + BN partial sums -----------
__global__ __launch_bounds__(256) void proj_gemm(
    const float* __restrict__ Opart, const float* __restrict__ W2,
    const float* __restrict__ b2, float* __restrict__ yT,
    float* __restrict__ stats)
{
  const int r0 = blockIdx.y * 64, c0 = blockIdx.x * 64;
  __shared__ alignas(16) float a_s[16][68];
  __shared__ alignas(16) float w_s[16][68];
  __shared__ float red[16][64];
  const int tid = threadIdx.x, tx = tid & 15, ty = tid >> 4;
  const float* O0 = Opart;
  const float* O1 = Opart + (size_t)MTOT * CC;
  const float* O2 = Opart + 2 * (size_t)MTOT * CC;
  float acc[4][4] = {};
  for (int ck = 0; ck < CC; ck += 16) {
#pragma unroll
    for (int t = 0; t < 4; ++t) {
      int e = tid + t * 256;
      const size_t gi = (size_t)(r0 + (e >> 4)) * CC + ck + (e & 15);
      a_s[e & 15][e >> 4] = O0[gi] + O1[gi] + O2[gi];  // inline split merge
      w_s[e & 15][e >> 4] = W2[(c0 + (e >> 4)) * CC + ck + (e & 15)];
    }
    __syncthreads();
#pragma unroll
    for (int kk = 0; kk < 16; ++kk) {
      F4 a4, w4;
      a4.v = *(const float4*)&a_s[kk][ty * 4];
      w4.v = *(const float4*)&w_s[kk][tx * 4];
#pragma unroll
      for (int i = 0; i < 4; ++i)
#pragma unroll
        for (int j = 0; j < 4; ++j) acc[i][j] += a4.f[i] * w4.f[j];
    }
    __syncthreads();
  }
#pragma unroll
  for (int j = 0; j < 4; ++j) {
    const float bj = b2[c0 + tx * 4 + j];
#pragma unroll
    for (int i = 0; i < 4; ++i) acc[i][j] += bj;
  }
#pragma unroll
  for (int i = 0; i < 4; ++i) {
    F4 v4;
#pragma unroll
    for (int j = 0; j < 4; ++j) v4.f[j] = acc[i][j];
    *(float4*)&yT[(size_t)(r0 + ty * 4 + i) * CC + c0 + tx * 4] = v4.v;
  }
  float cs[4] = {}, cq[4] = {};
#pragma unroll
  for (int i = 0; i < 4; ++i)
#pragma unroll
    for (int j = 0; j < 4; ++j) { cs[j] += acc[i][j]; cq[j] += acc[i][j] * acc[i][j]; }
#pragma unroll
  for (int j = 0; j < 4; ++j) red[ty][tx * 4 + j] = cs[j];
  __syncthreads();
  if (tid < 64) {
    float s = 0.f;
#pragma unroll
    for (int t = 0; t < 16; ++t) s += red[t][tid];
    atomicAdd(&stats[c0 + tid], s);
  }
  __syncthreads();
#pragma unroll
  for (int j = 0; j < 4; ++j) red[ty][tx * 4 + j] = cq[j];
  __syncthreads();
  if (tid < 64) {
    float s = 0.f;
#pragma unroll
    for (int t = 0; t < 16; ++t) s += red[t][tid];
    atomicAdd(&stats[CC + c0 + tid], s);
  }
}

// ---------------- kernel 3b: BN finalize + (n,c)->(c,n) transpose -----------------
__global__ __launch_bounds__(256) void bn_out(
    const float* __restrict__ yT, const float* __restrict__ stats,
    const float* __restrict__ gamma, const float* __restrict__ beta,
    float* __restrict__ out)
{
  const int b = blockIdx.z, n0 = blockIdx.y * 64, c0 = blockIdx.x * 64;
  __shared__ alignas(16) float t_s[64][68];
  __shared__ float aa[64], bbf[64];
  const int tid = threadIdx.x;
  if (tid < 64) {
    const int c = c0 + tid;
    const float mean = stats[c] * (1.0f / MTOT);
    const float var  = stats[CC + c] * (1.0f / MTOT) - mean * mean;
    const float rstd = rsqrtf(var + BN_EPS);
    const float a = rstd * gamma[c];
    aa[tid]  = a;
    bbf[tid] = beta[c] - mean * a;
  }
#pragma unroll
  for (int t = 0; t < 4; ++t) {
    int e4 = tid + t * 256;           // 1024 float4 = 64r x 16c4
    int r = e4 >> 4, c4 = e4 & 15;
    *(float4*)&t_s[r][c4 * 4] =
        *(const float4*)&yT[((size_t)b * NN + n0 + r) * CC + c0 + c4 * 4];
  }
  __syncthreads();
#pragma unroll
  for (int t = 0; t < 4; ++t) {
    int e4 = tid + t * 256;           // 1024 float4 = 64c x 16r4
    int cr = e4 >> 4, r4 = e4 & 15;
    const float a = aa[cr], bb2 = bbf[cr];
    F4 o4;
#pragma unroll
    for (int k = 0; k < 4; ++k) o4.f[k] = t_s[r4 * 4 + k][cr] * a + bb2;
    *(float4*)&out[((size_t)b * CC + c0 + cr) * NN + n0 + r4 * 4] = o4.v;
  }
}

extern "C" void kernel_launch(void* const* d_in, const int* in_sizes, int n_in,
                              void* d_out, int out_size, void* d_ws, size_t ws_size,
                              hipStream_t stream)
{
  (void)in_sizes; (void)n_in; (void)out_size; (void)ws_size;
  const float* x     = (const float*)d_in[0];
  const float* Wk    = (const float*)d_in[1];
  const float* Wq    = (const float*)d_in[2];
  const float* Wv    = (const float*)d_in[3];
  const float* W2    = (const float*)d_in[4];
  const float* b2    = (const float*)d_in[5];
  const float* gamma = (const float*)d_in[6];
  const float* beta  = (const float*)d_in[7];
  float* out = (float*)d_out;
  float* ws  = (float*)d_ws;

  const size_t SZ = (size_t)BB * NN * CC;   // 4,718,592 floats
  float* kT     = ws;
  float* qT     = ws + SZ;
  float* vT     = ws + 2 * SZ;
  float* Opart  = ws + 3 * SZ;              // NSPLIT * SZ
  float* pmax   = ws + (3 + NSPLIT) * SZ;   // NSPLIT * MTOT
  float* psum   = pmax + (size_t)NSPLIT * MTOT;
  float* rowmax = psum + (size_t)NSPLIT * MTOT;
  float* rowinv = rowmax + MTOT;
  float* stats  = rowinv + MTOT;            // 512 floats
  float* yT     = kT;                       // kT dead after attn_pv

  qkv_gemm   <<<dim3(4, 36, 24),      256, 0, stream>>>(x, Wk, Wq, Wv, kT, qT, vT);
  attn_stats <<<dim3(36, NSPLIT, 8),  256, 0, stream>>>(kT, qT, pmax, psum);
  merge_stats<<<dim3(MTOT / 256),     256, 0, stream>>>(pmax, psum, rowmax, rowinv);
  attn_pv    <<<dim3(36, NSPLIT, 8),  256, 0, stream>>>(kT, qT, vT, rowmax, rowinv, Opart);
  zero_stats <<<dim3(2),              256, 0, stream>>>(stats);
  proj_gemm  <<<dim3(4, 288),         256, 0, stream>>>(Opart, W2, b2, yT, stats);
  bn_out     <<<dim3(4, 36, 8),       256, 0, stream>>>(yT, stats, gamma, beta, out);
}

// Round 2
// 494.449 us; speedup vs baseline: 5.6670x; 5.6670x over previous
//
#include <hip/hip_runtime.h>
#include <math.h>

#define BN_EPS 1e-5f

typedef unsigned short ushort_t;
typedef unsigned int uint_t;

constexpr int BB   = 8;
constexpr int CC   = 256;
constexpr int NN   = 2304;            // 48*48
constexpr int MTOT = BB * NN;         // 18432
constexpr int NSPLIT = 3;             // m-splits in attention
constexpr int MTILES = 36;            // 2304/64
constexpr int MT_PER_SPLIT = 12;
constexpr size_t SZE = (size_t)BB * NN * CC;   // 4,718,592

typedef short bf16x8 __attribute__((ext_vector_type(8)));
typedef float f32x4  __attribute__((ext_vector_type(4)));

union F4 { float4 v; float f[4]; };
union US4 { ushort_t u[4]; uint2 v; };

__device__ __forceinline__ ushort_t f2bf(float f) {
  uint_t u = __float_as_uint(f);
  uint_t r = u + 0x7FFFu + ((u >> 16) & 1u);   // RNE; inputs finite
  return (ushort_t)(r >> 16);
}
__device__ __forceinline__ float bf2f(ushort_t h) {
  return __uint_as_float(((uint_t)h) << 16);
}

// ---------------- kernel 1: QKV fp32 GEMM -> bf16 hi/lo K,Q + tiled bf16 V^T ------
// kq layout: [b][n][c] bf16 (hi,lo).  v layout: vt2[b][mtile][c][mi] bf16 (m = mtile*64+mi)
__global__ __launch_bounds__(256) void qkv_gemm(
    const float* __restrict__ x, const float* __restrict__ Wk,
    const float* __restrict__ Wq, const float* __restrict__ Wv,
    ushort_t* __restrict__ khi, ushort_t* __restrict__ klo,
    ushort_t* __restrict__ qhi, ushort_t* __restrict__ qlo,
    ushort_t* __restrict__ vt2)
{
  const int mat = blockIdx.z >> 3;
  const int b   = blockIdx.z & 7;
  const int n0  = blockIdx.y * 64;
  const int c0  = blockIdx.x * 64;
  const float* Wm = (mat == 0) ? Wk : (mat == 1) ? Wq : Wv;

  __shared__ alignas(16) float a_s[16][64];   // [kk][n]
  __shared__ alignas(16) float w_s[16][68];   // [kk][c]
  const int tid = threadIdx.x;
  const int tx = tid & 15, ty = tid >> 4;
  float acc[4][4] = {};
  const float* xb = x + (size_t)b * CC * NN;
  for (int ck = 0; ck < CC; ck += 16) {
#pragma unroll
    for (int t = 0; t < 4; ++t) {
      int e = tid + t * 256;
      a_s[e >> 6][e & 63] = xb[(size_t)(ck + (e >> 6)) * NN + n0 + (e & 63)];
      w_s[e & 15][e >> 4] = Wm[(c0 + (e >> 4)) * CC + ck + (e & 15)];
    }
    __syncthreads();
#pragma unroll
    for (int kk = 0; kk < 16; ++kk) {
      F4 a4, w4;
      a4.v = *(const float4*)&a_s[kk][ty * 4];
      w4.v = *(const float4*)&w_s[kk][tx * 4];
#pragma unroll
      for (int i = 0; i < 4; ++i)
#pragma unroll
        for (int j = 0; j < 4; ++j) acc[i][j] += a4.f[i] * w4.f[j];
    }
    __syncthreads();
  }
  if (mat < 2) {
    ushort_t* hb = ((mat == 0) ? khi : qhi) + (size_t)b * NN * CC;
    ushort_t* lb = ((mat == 0) ? klo : qlo) + (size_t)b * NN * CC;
#pragma unroll
    for (int i = 0; i < 4; ++i) {
      US4 hv, lv;
#pragma unroll
      for (int j = 0; j < 4; ++j) {
        const float v = acc[i][j];
        const ushort_t h = f2bf(v);
        hv.u[j] = h;
        lv.u[j] = f2bf(v - bf2f(h));
      }
      const size_t o = (size_t)(n0 + ty * 4 + i) * CC + c0 + tx * 4;
      *(uint2*)&hb[o] = hv.v;
      *(uint2*)&lb[o] = lv.v;
    }
  } else {
    ushort_t* vb2 = vt2 + (((size_t)b * MTILES + (n0 >> 6)) * CC) * 64;
#pragma unroll
    for (int j = 0; j < 4; ++j) {
      US4 pv;
#pragma unroll
      for (int i = 0; i < 4; ++i) pv.u[i] = f2bf(acc[i][j]);
      *(uint2*)&vb2[(size_t)(c0 + tx * 4 + j) * 64 + ty * 4] = pv.v;
    }
  }
}

// ---------------- kernel 2: fused flash attention (MFMA, online softmax) ----------
// grid (36, NSPLIT, 8); block 256 = 4 waves; wave w owns n-rows [n0+16w, +16)
// S = Khi*Qhi + Khi*Qlo + Klo*Qhi (fp32 acc).  Writes unnormalized O_split + (M,L).
__global__ __launch_bounds__(256, 2) void attn_fused(
    const ushort_t* __restrict__ khi, const ushort_t* __restrict__ klo,
    const ushort_t* __restrict__ qhi, const ushort_t* __restrict__ qlo,
    const ushort_t* __restrict__ vt2,
    float* __restrict__ Opart, float* __restrict__ Ms, float* __restrict__ Ls)
{
  const int b = blockIdx.z, split = blockIdx.y;
  const int n0 = blockIdx.x * 64;
  const int tid = threadIdx.x;
  const int w = tid >> 6, lane = tid & 63;
  const int l15 = lane & 15, q = lane >> 4;

  // region0: union( Qhi/Qlo stage 2*[64][136], V stage [256][72] ) ; region1: P [4][16][72]
  __shared__ alignas(16) ushort_t smem[18432 + 4 * 16 * 72];
  ushort_t* Qh_s = smem;                  // [64][136]
  ushort_t* Ql_s = smem + 64 * 136;       // [64][136]
  ushort_t* V_s  = smem;                  // [256][72] (aliases Q region)
  ushort_t* P_s  = smem + 18432;          // [4][16][72]

  const ushort_t* kh_b = khi + (size_t)b * NN * CC;
  const ushort_t* kl_b = klo + (size_t)b * NN * CC;
  const ushort_t* qh_b = qhi + (size_t)b * NN * CC;
  const ushort_t* ql_b = qlo + (size_t)b * NN * CC;

  // cache K A-frags (verified A layout: A[row=lane&15][k=quad*8+j])
  bf16x8 Kh[8], Kl[8];
  const int nrow = n0 + w * 16 + l15;
#pragma unroll
  for (int cs = 0; cs < 8; ++cs) {
    Kh[cs] = *(const bf16x8*)&kh_b[(size_t)nrow * CC + cs * 32 + q * 8];
    Kl[cs] = *(const bf16x8*)&kl_b[(size_t)nrow * CC + cs * 32 + q * 8];
  }
  f32x4 O[16];
#pragma unroll
  for (int i = 0; i < 16; ++i) O[i] = (f32x4){0.f, 0.f, 0.f, 0.f};
  float rmax[4], rsum[4];
#pragma unroll
  for (int r = 0; r < 4; ++r) { rmax[r] = -INFINITY; rsum[r] = 0.f; }

  for (int t = 0; t < MT_PER_SPLIT; ++t) {
    const int mt = split * MT_PER_SPLIT + t;
    const int m0 = mt * 64;
    f32x4 acc[4];
#pragma unroll
    for (int ms = 0; ms < 4; ++ms) acc[ms] = (f32x4){0.f, 0.f, 0.f, 0.f};

#pragma unroll
    for (int ch = 0; ch < 2; ++ch) {          // c-halves of 128
#pragma unroll
      for (int tt = 0; tt < 4; ++tt) {        // stage Qhi/Qlo [64][128]
        int e = tid + tt * 256;
        int r = e >> 4, cc = e & 15;
        *(uint4*)&Qh_s[r * 136 + cc * 8] =
            *(const uint4*)&qh_b[(size_t)(m0 + r) * CC + ch * 128 + cc * 8];
        *(uint4*)&Ql_s[r * 136 + cc * 8] =
            *(const uint4*)&ql_b[(size_t)(m0 + r) * CC + ch * 128 + cc * 8];
      }
      __syncthreads();
#pragma unroll
      for (int cs = 0; cs < 4; ++cs) {
        const int gcs = ch * 4 + cs;
#pragma unroll
        for (int ms = 0; ms < 4; ++ms) {
          bf16x8 Bh = *(const bf16x8*)&Qh_s[(ms * 16 + l15) * 136 + cs * 32 + q * 8];
          bf16x8 Bl = *(const bf16x8*)&Ql_s[(ms * 16 + l15) * 136 + cs * 32 + q * 8];
          acc[ms] = __builtin_amdgcn_mfma_f32_16x16x32_bf16(Kh[gcs], Bh, acc[ms], 0, 0, 0);
          acc[ms] = __builtin_amdgcn_mfma_f32_16x16x32_bf16(Kh[gcs], Bl, acc[ms], 0, 0, 0);
          acc[ms] = __builtin_amdgcn_mfma_f32_16x16x32_bf16(Kl[gcs], Bh, acc[ms], 0, 0, 0);
        }
      }
      __syncthreads();
    }

    // ---- online softmax on S (C/D layout: col m = l15, row n = q*4+reg) ----
    float alpha[4];
#pragma unroll
    for (int r = 0; r < 4; ++r) {
      float tm = fmaxf(fmaxf(acc[0][r], acc[1][r]), fmaxf(acc[2][r], acc[3][r]));
#pragma unroll
      for (int off = 1; off < 16; off <<= 1) tm = fmaxf(tm, __shfl_xor(tm, off));
      const float Mn = fmaxf(rmax[r], tm);
      alpha[r] = __expf(rmax[r] - Mn);
      rmax[r] = Mn;
      float ps = 0.f;
#pragma unroll
      for (int ms = 0; ms < 4; ++ms) {
        const float p = __expf(acc[ms][r] - Mn);
        ps += p;
        P_s[(w * 16 + q * 4 + r) * 72 + ms * 16 + l15] = f2bf(p);   // wave-private
      }
#pragma unroll
      for (int off = 1; off < 16; off <<= 1) ps += __shfl_xor(ps, off);
      rsum[r] = rsum[r] * alpha[r] + ps;
    }
    const f32x4 av = {alpha[0], alpha[1], alpha[2], alpha[3]};
#pragma unroll
    for (int i = 0; i < 16; ++i) O[i] *= av;

    // ---- stage V tile [256 c][64 m] (Q region dead since last sync) ----
#pragma unroll
    for (int tt = 0; tt < 8; ++tt) {
      int e = tid + tt * 256;
      int r = e >> 3, cc = e & 7;
      *(uint4*)&V_s[r * 72 + cc * 8] =
          *(const uint4*)&vt2[(((size_t)b * MTILES + mt) * CC + r) * 64 + cc * 8];
    }
    __syncthreads();

    // ---- PV: O[n][cout] += P * V ----
#pragma unroll
    for (int ks = 0; ks < 2; ++ks) {
      bf16x8 Ap = *(const bf16x8*)&P_s[(w * 16 + l15) * 72 + ks * 32 + q * 8];
#pragma unroll
      for (int cs = 0; cs < 16; ++cs) {
        bf16x8 Bv = *(const bf16x8*)&V_s[(cs * 16 + l15) * 72 + ks * 32 + q * 8];
        O[cs] = __builtin_amdgcn_mfma_f32_16x16x32_bf16(Ap, Bv, O[cs], 0, 0, 0);
      }
    }
    __syncthreads();   // protect V_s/Q region before next m-tile staging
  }

  float* Ob = Opart + (size_t)split * SZE + (size_t)b * NN * CC;
#pragma unroll
  for (int cs = 0; cs < 16; ++cs)
#pragma unroll
    for (int r = 0; r < 4; ++r)
      Ob[(size_t)(n0 + w * 16 + q * 4 + r) * CC + cs * 16 + l15] = O[cs][r];
  if (l15 == 0) {
#pragma unroll
    for (int r = 0; r < 4; ++r) {
      const int n = n0 + w * 16 + q * 4 + r;
      Ms[(size_t)(split * BB + b) * NN + n] = rmax[r];
      Ls[(size_t)(split * BB + b) * NN + n] = rsum[r];
    }
  }
}

// ---------------- kernel 3: merge split softmax stats -> per-split row weights ----
__global__ void softmax_merge(const float* __restrict__ Ms, const float* __restrict__ Ls,
                              float* __restrict__ wsc)
{
  const int r = blockIdx.x * 256 + threadIdx.x;
  const float m0 = Ms[r], m1 = Ms[MTOT + r], m2 = Ms[2 * MTOT + r];
  const float M = fmaxf(m0, fmaxf(m1, m2));
  const float e0 = __expf(m0 - M), e1 = __expf(m1 - M), e2 = __expf(m2 - M);
  const float L = Ls[r] * e0 + Ls[MTOT + r] * e1 + Ls[2 * MTOT + r] * e2;
  const float inv = 1.0f / L;
  wsc[r] = e0 * inv; wsc[MTOT + r] = e1 * inv; wsc[2 * MTOT + r] = e2 * inv;
}

// ---------------- zero BN stats ---------------------------------------------------
__global__ void zero_stats(float* __restrict__ s)
{
  s[blockIdx.x * 256 + threadIdx.x] = 0.f;
}

// ---------------- kernel 4: projection + bias + BN partial sums -------------------
__global__ __launch_bounds__(256) void proj_gemm(
    const float* __restrict__ Opart, const float* __restrict__ wsc,
    const float* __restrict__ W2, const float* __restrict__ b2,
    float* __restrict__ yT, float* __restrict__ stats)
{
  const int r0 = blockIdx.y * 64, c0 = blockIdx.x * 64;
  __shared__ alignas(16) float a_s[16][68];
  __shared__ alignas(16) float w_s[16][68];
  __shared__ float red[16][64];
  const int tid = threadIdx.x, tx = tid & 15, ty = tid >> 4;
  const float* O0 = Opart;
  const float* O1 = Opart + SZE;
  const float* O2 = Opart + 2 * SZE;
  float acc[4][4] = {};
  for (int ck = 0; ck < CC; ck += 16) {
#pragma unroll
    for (int t = 0; t < 4; ++t) {
      int e = tid + t * 256;
      const int row = r0 + (e >> 4);
      const size_t gi = (size_t)row * CC + ck + (e & 15);
      a_s[e & 15][e >> 4] = O0[gi] * wsc[row] + O1[gi] * wsc[MTOT + row]
                          + O2[gi] * wsc[2 * MTOT + row];
      w_s[e & 15][e >> 4] = W2[(c0 + (e >> 4)) * CC + ck + (e & 15)];
    }
    __syncthreads();
#pragma unroll
    for (int kk = 0; kk < 16; ++kk) {
      F4 a4, w4;
      a4.v = *(const float4*)&a_s[kk][ty * 4];
      w4.v = *(const float4*)&w_s[kk][tx * 4];
#pragma unroll
      for (int i = 0; i < 4; ++i)
#pragma unroll
        for (int j = 0; j < 4; ++j) acc[i][j] += a4.f[i] * w4.f[j];
    }
    __syncthreads();
  }
#pragma unroll
  for (int j = 0; j < 4; ++j) {
    const float bj = b2[c0 + tx * 4 + j];
#pragma unroll
    for (int i = 0; i < 4; ++i) acc[i][j] += bj;
  }
#pragma unroll
  for (int i = 0; i < 4; ++i) {
    F4 v4;
#pragma unroll
    for (int j = 0; j < 4; ++j) v4.f[j] = acc[i][j];
    *(float4*)&yT[(size_t)(r0 + ty * 4 + i) * CC + c0 + tx * 4] = v4.v;
  }
  float cs[4] = {}, cq[4] = {};
#pragma unroll
  for (int i = 0; i < 4; ++i)
#pragma unroll
    for (int j = 0; j < 4; ++j) { cs[j] += acc[i][j]; cq[j] += acc[i][j] * acc[i][j]; }
#pragma unroll
  for (int j = 0; j < 4; ++j) red[ty][tx * 4 + j] = cs[j];
  __syncthreads();
  if (tid < 64) {
    float s = 0.f;
#pragma unroll
    for (int t = 0; t < 16; ++t) s += red[t][tid];
    atomicAdd(&stats[c0 + tid], s);
  }
  __syncthreads();
#pragma unroll
  for (int j = 0; j < 4; ++j) red[ty][tx * 4 + j] = cq[j];
  __syncthreads();
  if (tid < 64) {
    float s = 0.f;
#pragma unroll
    for (int t = 0; t < 16; ++t) s += red[t][tid];
    atomicAdd(&stats[CC + c0 + tid], s);
  }
}

// ---------------- kernel 5: BN finalize + (n,c)->(c,n) transpose ------------------
__global__ __launch_bounds__(256) void bn_out(
    const float* __restrict__ yT, const float* __restrict__ stats,
    const float* __restrict__ gamma, const float* __restrict__ beta,
    float* __restrict__ out)
{
  const int b = blockIdx.z, n0 = blockIdx.y * 64, c0 = blockIdx.x * 64;
  __shared__ alignas(16) float t_s[64][68];
  __shared__ float aa[64], bbf[64];
  const int tid = threadIdx.x;
  if (tid < 64) {
    const int c = c0 + tid;
    const float mean = stats[c] * (1.0f / MTOT);
    const float var  = stats[CC + c] * (1.0f / MTOT) - mean * mean;
    const float rstd = rsqrtf(var + BN_EPS);
    const float a = rstd * gamma[c];
    aa[tid]  = a;
    bbf[tid] = beta[c] - mean * a;
  }
#pragma unroll
  for (int t = 0; t < 4; ++t) {
    int e4 = tid + t * 256;
    int r = e4 >> 4, c4 = e4 & 15;
    *(float4*)&t_s[r][c4 * 4] =
        *(const float4*)&yT[((size_t)b * NN + n0 + r) * CC + c0 + c4 * 4];
  }
  __syncthreads();
#pragma unroll
  for (int t = 0; t < 4; ++t) {
    int e4 = tid + t * 256;
    int cr = e4 >> 4, r4 = e4 & 15;
    const float a = aa[cr], bb2 = bbf[cr];
    F4 o4;
#pragma unroll
    for (int k = 0; k < 4; ++k) o4.f[k] = t_s[r4 * 4 + k][cr] * a + bb2;
    *(float4*)&out[((size_t)b * CC + c0 + cr) * NN + n0 + r4 * 4] = o4.v;
  }
}

extern "C" void kernel_launch(void* const* d_in, const int* in_sizes, int n_in,
                              void* d_out, int out_size, void* d_ws, size_t ws_size,
                              hipStream_t stream)
{
  (void)in_sizes; (void)n_in; (void)out_size; (void)ws_size;
  const float* x     = (const float*)d_in[0];
  const float* Wk    = (const float*)d_in[1];
  const float* Wq    = (const float*)d_in[2];
  const float* Wv    = (const float*)d_in[3];
  const float* W2    = (const float*)d_in[4];
  const float* b2    = (const float*)d_in[5];
  const float* gamma = (const float*)d_in[6];
  const float* beta  = (const float*)d_in[7];
  float* out = (float*)d_out;

  ushort_t* u  = (ushort_t*)d_ws;
  ushort_t* khi = u;
  ushort_t* klo = u + SZE;
  ushort_t* qhi = u + 2 * SZE;
  ushort_t* qlo = u + 3 * SZE;
  ushort_t* vt2 = u + 4 * SZE;
  float* Opart = (float*)(u + 5 * SZE);     // 3*SZE floats
  float* Ms    = Opart + 3 * SZE;           // [NSPLIT][MTOT]
  float* Ls    = Ms + 3 * MTOT;
  float* wsc   = Ls + 3 * MTOT;
  float* stats = wsc + 3 * MTOT;            // 512
  float* yT    = (float*)d_ws;              // aliases khi/klo (dead after attn)

  qkv_gemm     <<<dim3(4, 36, 24),     256, 0, stream>>>(x, Wk, Wq, Wv, khi, klo, qhi, qlo, vt2);
  attn_fused   <<<dim3(36, NSPLIT, 8), 256, 0, stream>>>(khi, klo, qhi, qlo, vt2, Opart, Ms, Ls);
  softmax_merge<<<dim3(MTOT / 256),    256, 0, stream>>>(Ms, Ls, wsc);
  zero_stats   <<<dim3(2),             256, 0, stream>>>(stats);
  proj_gemm    <<<dim3(4, 288),        256, 0, stream>>>(Opart, wsc, W2, b2, yT, stats);
  bn_out       <<<dim3(4, 36, 8),      256, 0, stream>>>(yT, stats, gamma, beta, out);
}